// Round 1
// baseline (7177.867 us; speedup 1.0000x reference)
//
#include <hip/hip_runtime.h>
#include <math.h>

// LSTM: L=7, H=49, B=1024, T=512, I=7, O=7. fp32 in/out.
//
// Round 6: make the cross-layer pipeline ACTUALLY RUN.
//  - R5 post-mortem (rocprof): the top dispatches were lstm_fb — the R5
//    pipelined kernel never executed. Its full-size rings needed 763 MB of
//    workspace; the harness provides less, so the fallback branch ran
//    (7 serial latency-bound layer kernels @ ~522 us = 3.36 ms total,
//    HBM 3.7%, MfmaUtil 29%, Occupancy 20%).
//  - Fix 1 (fit): rings shrink to RW=8-block (64-step) wraparound windows:
//    6 rings x 1024 samp x 8 blk x 8 steps x 52 cols fp32 = 78 MiB. The
//    fallback already proved >=98 MiB available (it wrote hbuf[B,T,49]
//    into d_ws and passed), so this path now engages.
//  - Fix 2 (flow control): consumer publishes cons_flag = #blocks fully
//    loaded (vmcnt-drained) once per 8 steps; producer polls it before
//    overwriting slot k%RW (needs cons >= k-RW+1). Steady-state skew
//    ~13 steps << 64-step window -> producers rarely stall. All 448 WGs
//    co-resident: 7 waves/WG, launch_bounds(448,4) caps VGPR at 128 ->
//    2 WG/CU -> 512 slots >= 448. blockIdx = 64*l + grp puts each
//    producer/consumer pair on the same XCD under round-robin dispatch
//    (perf only; agent-scope release/acquire is correct regardless).
//  - Fix 3 (NaN hazard in the R5 path): ring pad cols 49..51 were never
//    written -> uninitialized ws could be NaN; NaN*0 poisons MFMA. The
//    v0-invalid lanes (wave 6, quads 1..3 = exactly j0 49..51) store 0.
//  - Fix 4 (footprint): FC fused into layer 6 via LDS h_sh[parity] —
//    removes the 109 MB layer-6 ring and the separate fc kernel.
//  - Compute core (proven by the passing fallback): MFMA 16x16x32 bf16,
//    3-pass hi/lo split, 13 N-tiles of 16 gate-interleaved rows, bias via
//    MFMA C-init, wave-local preT, c-state in regs, A planes double-
//    buffered by parity, lgkm-only barrier per step.

constexpr int TT = 512;
constexpr int BB = 1024;
constexpr int HH = 49;
constexpr int GG = 196;

constexpr int RW = 8;                               // ring window (blocks, pow2)
constexpr size_t R_SAMP      = (size_t)RW * 416;    // floats per sample
constexpr size_t R_LAYER     = 1024ull * R_SAMP;    // floats per ring (layer)
constexpr size_t RING_FLOATS = 6ull * R_LAYER;      // rings for layers 0..5
constexpr size_t FLAG_INTS   = 12ull * 64 * 32;     // [0..5]=prod, [6..11]=cons
constexpr size_t WS_NEEDED   = RING_FLOATS * 4 + FLAG_INTS * 4;   // ~78 MiB

typedef __attribute__((ext_vector_type(8))) short short8;
typedef __attribute__((ext_vector_type(4))) short short4v;
typedef __attribute__((ext_vector_type(4))) float f32x4;

__device__ __forceinline__ float sigmoidf_(float x) {
    return 1.0f / (1.0f + __expf(-x));
}
__device__ __forceinline__ float tanhf_(float x) {
    return 1.0f - 2.0f / (1.0f + __expf(2.0f * x));
}

__device__ __forceinline__ void bf16split(float x, short& hi, short& lo) {
    unsigned u = __float_as_uint(x);
    unsigned r = u + 0x7FFFu + ((u >> 16) & 1u);
    hi = (short)(r >> 16);
    float fhi = __uint_as_float(r & 0xFFFF0000u);
    float rem = x - fhi;
    unsigned u2 = __float_as_uint(rem);
    unsigned r2 = u2 + 0x7FFFu + ((u2 >> 16) & 1u);
    lo = (short)(r2 >> 16);
}

// fragment-order element address (2B units) of A[m][k], m<16, k<128
__device__ __forceinline__ int addr2B(int m, int k) {
    return (k >> 5) * 512 + ((k >> 3) & 3) * 128 + m * 8 + (k & 7);
}

#define WGBAR() asm volatile("s_waitcnt lgkmcnt(0)\n\ts_barrier" ::: "memory")
#define VMDRAIN() asm volatile("s_waitcnt vmcnt(0)" ::: "memory")

__global__ void zero_flags(int* f, int n) {
    int i = blockIdx.x * 256 + threadIdx.x;
    if (i < n) f[i] = 0;
}

__global__ __launch_bounds__(448, 4)
void lstm_pipe(const float* __restrict__ xin,    // [B,T,7]
               float* __restrict__ ring,         // [6][1024][RW][8][52]
               int* __restrict__ flags,          // [12][64][32]
               const float* __restrict__ Wih0,   // [196,7]
               const float* __restrict__ Wihr,   // [6,196,49]
               const float* __restrict__ Whh,    // [7,196,49]
               const float* __restrict__ bih,    // [7,196]
               const float* __restrict__ bhh,    // [7,196]
               const float* __restrict__ fcw,    // [7,49]
               const float* __restrict__ fcb,    // [7]
               float* __restrict__ outp)         // [B,T,7]
{
    __shared__ __align__(16) short Ahi[2][2048];     // [parity][frag order]
    __shared__ __align__(16) short Alo[2][2048];
    __shared__ __align__(16) float preT[13 * 16 * 20];
    __shared__ __align__(16) float h_sh[2][16][52];  // layer-6 h, by parity
    __shared__ __align__(16) float w7[7][52];        // fc weights (padded 0)
    __shared__ float bsh[8];

    const int tid  = threadIdx.x;
    const int wave = tid >> 6;
    const int lane = tid & 63;
    const int quad = lane >> 4;
    const int lrow = lane & 15;

    const int l   = blockIdx.x >> 6;             // layer 0..6
    const int grp = blockIdx.x & 63;             // sample group
    const int b0  = grp << 4;                    // 16 samples

    const int DIN  = (l == 0) ? 7 : 49;
    const int KSRT = (l == 0) ? 2 : 4;           // active k-steps
    const float* Wih = (l == 0) ? Wih0 : (Wihr + (size_t)(l - 1) * GG * HH);
    const float* Whl = Whh + (size_t)l * GG * HH;
    const float* bi  = bih + (size_t)l * GG;
    const float* bh  = bhh + (size_t)l * GG;

    const int lm1 = (l > 0) ? (l - 1) : 0;
    const int lp  = (l < 6) ? l : 0;
    const float* rin  = ring + (size_t)lm1 * R_LAYER;
    float*       rout = ring + (size_t)lp  * R_LAYER;
    int* flag_in   = flags + (size_t)lm1 * 2048 + (size_t)grp * 32;       // prod(ring l-1)
    int* cons_sig  = flags + (size_t)(6 + lm1) * 2048 + (size_t)grp * 32; // we consumed l-1
    int* flag_out  = flags + (size_t)lp * 2048 + (size_t)grp * 32;        // prod(ring l)
    int* cons_poll = flags + (size_t)(6 + lp) * 2048 + (size_t)grp * 32;  // consumer of l
    const bool wr = (l < 6);                     // layer 6 has no output ring

    const int ntiles = (wave < 6) ? 2 : 1;
    const int tA = (wave < 6) ? wave : 12;
    const int tB = wave + 6;                     // valid if wave<6

    // ---- B fragments (hi/lo) + bias in VGPRs -----------------------------
    short8 BH[2][4], BL[2][4];
    float  biasv[2];
    #pragma unroll
    for (int ti = 0; ti < 2; ++ti) {
        const int  nt    = ti ? tB : tA;
        const bool valid = (ti < ntiles) && (nt < 13);
        const int  np    = nt * 16 + lrow;       // permuted row r' = 4j+gate
        const int  j     = np >> 2;
        const int  g     = np & 3;
        const bool jb    = valid && (j < HH);
        biasv[ti] = jb ? (bi[g * HH + j] + bh[g * HH + j]) : 0.0f;
        #pragma unroll
        for (int ks = 0; ks < 4; ++ks) {
            #pragma unroll
            for (int jj = 0; jj < 8; ++jj) {
                const int k = ks * 32 + quad * 8 + jj;
                float wv = 0.0f;
                if (jb) {
                    const int r = g * HH + j;
                    if (k < HH)                       wv = Whl[r * HH + k];
                    else if (k >= 52 && k < 52 + DIN) wv = Wih[r * DIN + (k - 52)];
                }
                short h_, l_;
                bf16split(wv, h_, l_);
                BH[ti][ks][jj] = h_;
                BL[ti][ks][jj] = l_;
            }
        }
    }

    // ---- EW cells: lane owns (tile, j = 4*nt+quad, sample s = lrow) ------
    const int  j0 = 4 * tA + quad;
    const int  j1 = 4 * tB + quad;
    const bool v0 = (j0 < HH);                   // false only wave6 quads 1..3
    const bool v1 = (wave < 6);                  // then j1<=47<49
    const int  ah0 = addr2B(lrow, j0);
    const int  ah1 = addr2B(lrow, j1);
    float* rc0 = rout + (size_t)(b0 + lrow) * R_SAMP + j0;
    float* rc1 = rout + (size_t)(b0 + lrow) * R_SAMP + j1;
    float cc0 = 0.0f, cc1 = 0.0f;

    // ---- loader role -----------------------------------------------------
    bool is_ld;
    int  ld_m, ld_kx, a_st;
    const float* gb;                             // per-lane load base
    if (l == 0) {
        is_ld = (tid < 112);                     // 16 samples x 7 cols
        ld_m  = tid / 7;
        ld_kx = tid - ld_m * 7;
        a_st  = addr2B(ld_m & 15, 52 + ld_kx);
        gb    = xin + ((size_t)(b0 + (ld_m & 15)) * TT) * 7 + ld_kx;
    } else {
        is_ld = (tid < 208);                     // 16 samples x 13 quads
        ld_m  = tid / 13;
        ld_kx = tid - ld_m * 13;                 // k-quad
        a_st  = addr2B(ld_m & 15, 52 + 4 * ld_kx);
        gb    = rin + (size_t)(b0 + (ld_m & 15)) * R_SAMP + 4 * ld_kx;
    }

    // ---- init ------------------------------------------------------------
    for (int i = tid; i < 2048; i += 448) {
        ((unsigned*)Ahi)[i] = 0u;
        ((unsigned*)Alo)[i] = 0u;
    }
    if (l == 6) {
        for (int i = tid; i < 2 * 16 * 52; i += 448) ((float*)h_sh)[i] = 0.0f;
        for (int i = tid; i < 7 * 52; i += 448) {
            const int o = i / 52, k = i - o * 52;
            w7[o][k] = (k < HH) ? fcw[o * HH + k] : 0.0f;
        }
        if (tid < 7) bsh[tid] = fcb[tid];
    }
    __syncthreads();

    if (l > 0) {                                 // wait for input block 0
        if (tid == 0) {
            while (__hip_atomic_load(flag_in, __ATOMIC_ACQUIRE,
                                     __HIP_MEMORY_SCOPE_AGENT) < 1)
                __builtin_amdgcn_s_sleep(8);
        }
        __syncthreads();
        __builtin_amdgcn_fence(__ATOMIC_ACQUIRE, "agent");
    }

    // prologue loads: t'=0 and t'=1 (both in block 0, slot 0)
    float4 xr0 = {0, 0, 0, 0}, xr1 = {0, 0, 0, 0};
    if (is_ld) {
        if (l == 0) { xr0.x = gb[0]; xr1.x = gb[7]; }
        else        { xr0 = *(const float4*)gb; xr1 = *(const float4*)(gb + 52); }
    }

    // stage x_0 -> A[0]
    if (is_ld) {
        if (l == 0) {
            short h_, l_;
            bf16split(xr0.x, h_, l_);
            Ahi[0][a_st] = h_; Alo[0][a_st] = l_;
        } else {
            short h0,l0_,h1,l1_,h2,l2_,h3,l3_;
            bf16split(xr0.x,h0,l0_); bf16split(xr0.y,h1,l1_);
            bf16split(xr0.z,h2,l2_); bf16split(xr0.w,h3,l3_);
            short4v vh = {h0,h1,h2,h3}, vl = {l0_,l1_,l2_,l3_};
            *(short4v*)&Ahi[0][a_st] = vh;
            *(short4v*)&Alo[0][a_st] = vl;
        }
    }
    __syncthreads();

    // ---- scan ------------------------------------------------------------
    for (int t = 0; t < TT; ++t) {
        const int p  = t & 1;
        const int tb = t & 7;

        // producer chores: drain block k-1 stores, then publish it
        if (wr && tb == 2) VMDRAIN();            // stores of block (t>>3)-1 done
        if (wr && tb == 3 && (t >> 3) >= 1 && tid == 0)
            __hip_atomic_store(flag_out, t >> 3, __ATOMIC_RELEASE,
                               __HIP_MEMORY_SCOPE_AGENT);

        // consumer chores: signal consumed block, gate the next one
        if (l > 0 && tb == 6) {
            VMDRAIN();                           // all block-(t>>3) loads done
            __syncthreads();
            if (tid == 0)                        // blocks 0..t>>3 consumed
                __hip_atomic_store(cons_sig, (t >> 3) + 1, __ATOMIC_RELEASE,
                                   __HIP_MEMORY_SCOPE_AGENT);
            if ((t + 2) < TT) {
                if (tid == 0) {
                    const int want = ((t + 2) >> 3) + 1;
                    while (__hip_atomic_load(flag_in, __ATOMIC_ACQUIRE,
                                             __HIP_MEMORY_SCOPE_AGENT) < want)
                        __builtin_amdgcn_s_sleep(8);
                }
                WGBAR();
                __builtin_amdgcn_fence(__ATOMIC_ACQUIRE, "agent");
            }
        }

        // issue prefetch load for t+2 (after any acquire fence)
        float4 xnew = {0, 0, 0, 0};
        const bool ldnow = is_ld && (t + 2) < TT;
        if (ldnow) {
            if (l == 0) xnew.x = gb[(size_t)(t + 2) * 7];
            else {
                const int offn = (((t + 2) >> 3) & (RW - 1)) * 416
                               + ((t + 2) & 7) * 52;
                xnew = *(const float4*)(gb + offn);
            }
        }

        // A fragments (parity p), conflict-free b128
        short8 AH[4], AL[4];
        #pragma unroll
        for (int ks = 0; ks < 4; ++ks) {
            if (ks < KSRT) {
                AH[ks] = *(const short8*)&Ahi[p][ks * 512 + lane * 8];
                AL[ks] = *(const short8*)&Alo[p][ks * 512 + lane * 8];
            }
        }

        // MFMA: tile A (all waves) + tile B (waves 0..5)
        f32x4 C0 = {biasv[0], biasv[0], biasv[0], biasv[0]};
        #pragma unroll
        for (int ks = 0; ks < 4; ++ks) {
            if (ks < KSRT) {
                C0 = __builtin_amdgcn_mfma_f32_16x16x32_bf16(AH[ks], BH[0][ks], C0, 0, 0, 0);
                C0 = __builtin_amdgcn_mfma_f32_16x16x32_bf16(AL[ks], BH[0][ks], C0, 0, 0, 0);
                C0 = __builtin_amdgcn_mfma_f32_16x16x32_bf16(AH[ks], BL[0][ks], C0, 0, 0, 0);
            }
        }
        #pragma unroll
        for (int r = 0; r < 4; ++r)
            preT[(tA * 16 + 4 * quad + r) * 20 + lrow] = C0[r];

        if (wave < 6) {
            f32x4 C1 = {biasv[1], biasv[1], biasv[1], biasv[1]};
            #pragma unroll
            for (int ks = 0; ks < 4; ++ks) {
                if (ks < KSRT) {
                    C1 = __builtin_amdgcn_mfma_f32_16x16x32_bf16(AH[ks], BH[1][ks], C1, 0, 0, 0);
                    C1 = __builtin_amdgcn_mfma_f32_16x16x32_bf16(AL[ks], BH[1][ks], C1, 0, 0, 0);
                    C1 = __builtin_amdgcn_mfma_f32_16x16x32_bf16(AH[ks], BL[1][ks], C1, 0, 0, 0);
                }
            }
            #pragma unroll
            for (int r = 0; r < 4; ++r)
                preT[(tB * 16 + 4 * quad + r) * 20 + lrow] = C1[r];
        }

        // fused FC (layer 6): consume h_{t-1} from h_sh[p] (disjoint from
        // this step's h_sh[p^1] writes; made visible by last step's WGBAR)
        if (l == 6 && t > 0 && tid < 112) {
            const int s = tid / 7;
            const int o = tid - s * 7;
            const float* hr = h_sh[p][s];
            float acc = bsh[o];
            #pragma unroll
            for (int k = 0; k < 52; k += 4) {
                const f32x4 hv4 = *(const f32x4*)&hr[k];
                const f32x4 wv4 = *(const f32x4*)&w7[o][k];
                acc = fmaf(hv4.x, wv4.x, acc);
                acc = fmaf(hv4.y, wv4.y, acc);
                acc = fmaf(hv4.z, wv4.z, acc);
                acc = fmaf(hv4.w, wv4.w, acc);
            }
            outp[((size_t)(b0 + s) * TT + (t - 1)) * 7 + o] = acc;
        }

        // EW (wave-local preT read-after-write; lgkm ordering in-wave)
        const int offc = ((t >> 3) & (RW - 1)) * 416 + tb * 52;
        if (v0) {
            const f32x4 gt = *(const f32x4*)&preT[(tA * 16 + lrow) * 20 + 4 * quad];
            const float i_ = sigmoidf_(gt.x);
            const float f_ = sigmoidf_(gt.y);
            const float g_ = tanhf_(gt.z);
            const float o_ = sigmoidf_(gt.w);
            cc0 = f_ * cc0 + i_ * g_;
            const float hv = o_ * tanhf_(cc0);
            short hh, hl;
            bf16split(hv, hh, hl);
            Ahi[p ^ 1][ah0] = hh;
            Alo[p ^ 1][ah0] = hl;
            if (wr) rc0[offc] = hv;
            else    h_sh[p ^ 1][lrow][j0] = hv;
        } else if (wr) {
            rc0[offc] = 0.0f;                    // pad cols 49..51: NaN-free
        }
        if (v1) {
            const f32x4 gt = *(const f32x4*)&preT[(tB * 16 + lrow) * 20 + 4 * quad];
            const float i_ = sigmoidf_(gt.x);
            const float f_ = sigmoidf_(gt.y);
            const float g_ = tanhf_(gt.z);
            const float o_ = sigmoidf_(gt.w);
            cc1 = f_ * cc1 + i_ * g_;
            const float hv = o_ * tanhf_(cc1);
            short hh, hl;
            bf16split(hv, hh, hl);
            Ahi[p ^ 1][ah1] = hh;
            Alo[p ^ 1][ah1] = hl;
            if (wr) rc1[offc] = hv;
            else    h_sh[p ^ 1][lrow][j1] = hv;
        }

        // stage x_{t+1} -> A[p^1] from the reg slot loaded at t-1
        if (is_ld && (t + 1) < TT) {
            const float4 xv = ((t + 1) & 1) ? xr1 : xr0;
            if (l == 0) {
                short h_, l_;
                bf16split(xv.x, h_, l_);
                Ahi[p ^ 1][a_st] = h_; Alo[p ^ 1][a_st] = l_;
            } else {
                short h0,l0_,h1,l1_,h2,l2_,h3,l3_;
                bf16split(xv.x,h0,l0_); bf16split(xv.y,h1,l1_);
                bf16split(xv.z,h2,l2_); bf16split(xv.w,h3,l3_);
                short4v vh = {h0,h1,h2,h3}, vl = {l0_,l1_,l2_,l3_};
                *(short4v*)&Ahi[p ^ 1][a_st] = vh;
                *(short4v*)&Alo[p ^ 1][a_st] = vl;
            }
        }
        if (ldnow) { if (t & 1) xr1 = xnew; else xr0 = xnew; }

        // producer wrap gate: before entering block k=(t+1)>>3, slot k%RW
        // must be consumed (cons >= k-RW+1). tid0 polls; the step-end
        // barrier holds everyone else; stores of block k come after it.
        if (wr && tb == 7 && (t + 1) < TT && ((t + 1) >> 3) >= RW && tid == 0) {
            const int need = ((t + 1) >> 3) - RW + 1;
            while (__hip_atomic_load(cons_poll, __ATOMIC_ACQUIRE,
                                     __HIP_MEMORY_SCOPE_AGENT) < need)
                __builtin_amdgcn_s_sleep(8);
        }

        WGBAR();   // lgkm-only: A[p^1] + preT + h_sh reuse safe for next step
    }

    // fused FC epilogue: h_511 was written to h_sh[0] (t=511, p=1)
    if (l == 6 && tid < 112) {
        const int s = tid / 7;
        const int o = tid - s * 7;
        const float* hr = h_sh[0][s];
        float acc = bsh[o];
        #pragma unroll
        for (int k = 0; k < 52; k += 4) {
            const f32x4 hv4 = *(const f32x4*)&hr[k];
            const f32x4 wv4 = *(const f32x4*)&w7[o][k];
            acc = fmaf(hv4.x, wv4.x, acc);
            acc = fmaf(hv4.y, wv4.y, acc);
            acc = fmaf(hv4.z, wv4.z, acc);
            acc = fmaf(hv4.w, wv4.w, acc);
        }
        outp[((size_t)(b0 + s) * TT + 511) * 7 + o] = acc;
    }

    // epilogue: publish completion (covers blocks 56..63)
    if (wr) {
        VMDRAIN();
        __syncthreads();
        if (tid == 0)
            __hip_atomic_store(flag_out, 64, __ATOMIC_RELEASE,
                               __HIP_MEMORY_SCOPE_AGENT);
    }
}

// ======================= fallback path (R4, per-layer) ======================

template<int DIN>
__global__ __launch_bounds__(448)
void lstm_fb(const float* xin, float* hout,
             const float* __restrict__ Wih, const float* __restrict__ Whh,
             const float* __restrict__ bihp, const float* __restrict__ bhhp)
{
    constexpr int XO = 52;
    constexpr int KTOT = XO + DIN;
    constexpr int KSTEPS = (KTOT + 31) / 32;
    __shared__ short Ahi[2][KSTEPS * 512];
    __shared__ short Alo[2][KSTEPS * 512];
    __shared__ float preT[13 * 64];

    const int tid = threadIdx.x, wave = tid >> 6, lane = tid & 63;
    const int quad = lane >> 4, lrow = lane & 15;
    const int b0 = blockIdx.x * 4;
    const int ntiles = (wave < 6) ? 2 : 1;
    const int tileA = (wave < 6) ? wave : 12;
    const int tileB = wave + 6;

    short8 BH[2][KSTEPS], BL[2][KSTEPS];
    float biasv[2];
    #pragma unroll
    for (int ti = 0; ti < 2; ++ti) {
        const int nt = ti ? tileB : tileA;
        const bool valid = (ti < ntiles);
        const int np = nt * 16 + lrow, j = np >> 2, g = np & 3;
        biasv[ti] = (valid && j < HH) ? (bihp[g*HH+j] + bhhp[g*HH+j]) : 0.0f;
        #pragma unroll
        for (int ks = 0; ks < KSTEPS; ++ks)
            #pragma unroll
            for (int jj = 0; jj < 8; ++jj) {
                const int k = ks * 32 + quad * 8 + jj;
                float wv = 0.0f;
                if (valid && j < HH) {
                    const int r = g * HH + j;
                    if (k < HH) wv = Whh[r * HH + k];
                    else if (k >= XO && k < KTOT) wv = Wih[r * DIN + (k - XO)];
                }
                short h_, l_; bf16split(wv, h_, l_);
                BH[ti][ks][jj] = h_; BL[ti][ks][jj] = l_;
            }
    }

    const int ec = lane & 15, ew_jj = ec >> 2, ew_m = ec & 3, ew_ti = lane >> 4;
    const bool is_ew = (lane < 32) && (ew_ti < ntiles);
    const int ew_nt = ew_ti ? tileB : tileA;
    const int ew_j = 4 * ew_nt + ew_jj;
    const bool ew_ok = is_ew && (ew_j < HH);
    const int pa0 = (ew_nt*16 + 4*ew_jj + 0)*4 + ew_m;
    const int pa1 = (ew_nt*16 + 4*ew_jj + 1)*4 + ew_m;
    const int pa2 = (ew_nt*16 + 4*ew_jj + 2)*4 + ew_m;
    const int pa3 = (ew_nt*16 + 4*ew_jj + 3)*4 + ew_m;
    const int ew_ah = addr2B(ew_m, ew_j);
    float cc = 0.0f;

    const int lx = tid;
    const bool is_loader = (lx < 4 * DIN);
    const int ld_m = is_loader ? (lx & 3) : 0, ld_k = is_loader ? (lx >> 2) : 0;
    const int xaddr = addr2B(ld_m, XO + ld_k);
    const size_t xbase = ((size_t)(b0 + ld_m) * TT) * DIN + ld_k;
    float* houtp = hout + ((size_t)(b0 + ew_m) * TT) * HH + (ew_ok ? ew_j : 0);

    for (int i = tid; i < KSTEPS * 512; i += 448) {
        ((unsigned*)Ahi)[i] = 0u; ((unsigned*)Alo)[i] = 0u;
    }
    __syncthreads();
    if (is_loader) {
        short h_, l_; bf16split(xin[xbase], h_, l_);
        Ahi[0][xaddr] = h_; Alo[0][xaddr] = l_;
    }
    __syncthreads();

    for (int t = 0; t < TT; ++t) {
        const int p = t & 1;
        float xnext = 0.0f;
        if (is_loader && (t + 1 < TT)) xnext = xin[xbase + (size_t)(t+1) * DIN];

        short8 AH[KSTEPS], AL[KSTEPS];
        #pragma unroll
        for (int ks = 0; ks < KSTEPS; ++ks) {
            AH[ks] = *(const short8*)&Ahi[p][ks * 512 + lane * 8];
            AL[ks] = *(const short8*)&Alo[p][ks * 512 + lane * 8];
        }
        #pragma unroll
        for (int ti = 0; ti < 2; ++ti) {
            f32x4 C = {biasv[ti], biasv[ti], biasv[ti], biasv[ti]};
            #pragma unroll
            for (int ks = 0; ks < KSTEPS; ++ks) {
                C = __builtin_amdgcn_mfma_f32_16x16x32_bf16(AH[ks], BH[ti][ks], C, 0, 0, 0);
                C = __builtin_amdgcn_mfma_f32_16x16x32_bf16(AL[ks], BH[ti][ks], C, 0, 0, 0);
                C = __builtin_amdgcn_mfma_f32_16x16x32_bf16(AH[ks], BL[ti][ks], C, 0, 0, 0);
            }
            if (ti < ntiles && lane < 16) {
                const int nt = ti ? tileB : tileA;
                *(f32x4*)&preT[(nt * 16 + lrow) * 4] = C;
            }
        }
        if (is_ew) {
            const float i_ = sigmoidf_(preT[pa0]);
            const float f_ = sigmoidf_(preT[pa1]);
            const float g_ = tanhf_(preT[pa2]);
            const float o_ = sigmoidf_(preT[pa3]);
            cc = f_ * cc + i_ * g_;
            const float hv = o_ * tanhf_(cc);
            if (ew_ok) {
                short hh, hl; bf16split(hv, hh, hl);
                Ahi[p ^ 1][ew_ah] = hh; Alo[p ^ 1][ew_ah] = hl;
                houtp[(size_t)t * HH] = hv;
            }
        }
        if (is_loader && (t + 1 < TT)) {
            short h_, l_; bf16split(xnext, h_, l_);
            Ahi[p ^ 1][xaddr] = h_; Alo[p ^ 1][xaddr] = l_;
        }
        __syncthreads();
    }
}

__global__ __launch_bounds__(256)
void fc_fb(const float* __restrict__ hbuf, const float* __restrict__ fcw,
           const float* __restrict__ fcb, float* __restrict__ outp)
{
    constexpr int HP = 52;
    __shared__ float w[7][HP];
    __shared__ float bsh[8];
    const int tid = threadIdx.x;
    for (int i = tid; i < 7 * HP; i += 256) {
        const int o = i / HP, k = i - o * HP;
        w[o][k] = (k < HH) ? fcw[o * HH + k] : 0.0f;
    }
    if (tid < 7) bsh[tid] = fcb[tid];
    __syncthreads();
    const size_t i = (size_t)blockIdx.x * 256 + tid;
    float acc[7];
    #pragma unroll
    for (int j = 0; j < 7; ++j) acc[j] = bsh[j];
    const float* hp = hbuf + i * HH;
    #pragma unroll
    for (int k = 0; k < HH; ++k) {
        const float hv = hp[k];
        #pragma unroll
        for (int j = 0; j < 7; ++j) acc[j] = fmaf(hv, w[j][k], acc[j]);
    }
    #pragma unroll
    for (int j = 0; j < 7; ++j) outp[i * 7 + j] = acc[j];
}

extern "C" void kernel_launch(void* const* d_in, const int* in_sizes, int n_in,
                              void* d_out, int out_size, void* d_ws, size_t ws_size,
                              hipStream_t stream)
{
    const float* x    = (const float*)d_in[0];
    const float* Wih0 = (const float*)d_in[1];
    const float* Wihr = (const float*)d_in[2];
    const float* Whh  = (const float*)d_in[3];
    const float* bih  = (const float*)d_in[4];
    const float* bhh  = (const float*)d_in[5];
    const float* fcw  = (const float*)d_in[6];
    const float* fcb  = (const float*)d_in[7];
    float* outp = (float*)d_out;

    if (ws_size >= WS_NEEDED) {
        float* ring  = (float*)d_ws;
        int*   flags = (int*)((char*)d_ws + RING_FLOATS * 4);
        zero_flags<<<(int)((FLAG_INTS + 255) / 256), 256, 0, stream>>>(
            flags, (int)FLAG_INTS);
        lstm_pipe<<<448, 448, 0, stream>>>(x, ring, flags, Wih0, Wihr,
                                           Whh, bih, bhh, fcw, fcb, outp);
    } else {
        float* hbuf = (float*)d_ws;   // [B,T,49]
        lstm_fb<7><<<BB / 4, 448, 0, stream>>>(x, hbuf, Wih0, Whh, bih, bhh);
        for (int l = 1; l < 7; ++l) {
            lstm_fb<49><<<BB / 4, 448, 0, stream>>>(
                hbuf, hbuf,
                Wihr + (size_t)(l - 1) * GG * HH,
                Whh  + (size_t)l * GG * HH,
                bih  + (size_t)l * GG,
                bhh  + (size_t)l * GG);
        }
        fc_fb<<<(BB * TT) / 256, 256, 0, stream>>>(hbuf, fcw, fcb, outp);
    }
}

// Round 2
// 2991.895 us; speedup vs baseline: 2.3991x; 2.3991x over previous
//
#include <hip/hip_runtime.h>
#include <math.h>

// LSTM: L=7, H=49, B=1024, T=512, I=7, O=7. fp32 in/out.
//
// Round 7: de-fence the cross-layer pipeline.
//  - R6 post-mortem (rocprof): lstm_pipe ran but 7219 us (2.1x WORSE than
//    fallback). Same work stretched 13.8x: VALUBusy 8.4% / MfmaUtil 3.0%
//    match the fallback's per-step work divided by the stall factor. FETCH
//    425 MB (8x), WRITE 1.05 GB (10x): the agent-scope acquire/release
//    fences (448 WGs x every 8 steps) invalidate/write back per-XCD L2s
//    ~28K times, destroying locality and putting HBM-latency store acks on
//    the per-step critical path.
//  - Fix: NO cache-maintenance ops at all. Ring data moves as RELAXED
//    agent-scope atomics (stores: dword sc1 write-through to MALL; loads:
//    dwordx2 sc1, L1/L2-bypass, served from the 256MB L3 - coherent across
//    XCDs by construction). Ordering is physical: producer VMDRAIN
//    (acks = data at MALL) -> relaxed flag store; consumer poll is a
//    dependent branch -> its loads issue after. No fences anywhere.
//  - Race fix: R6 signaled "block m consumed" at tb==6 BEFORE the last
//    block-m load (x_{8m+7}, issued at tb==6 phase D). Signal moved to
//    tb==7 behind a VMDRAIN.
//  - Prefetch simplified to the fallback-proven same-step pattern: load
//    x_{t+1} at top of step t (atomic, compiler-tracked), stage at bottom;
//    ~1500cy of MFMA/EW hides ~1000cy L3 latency. Removes the reg-copy /
//    manual-vmcnt hazard of the 2-step double-buffer.
//  - Everything else (MFMA core, preT, parity A-planes, fused FC in layer
//    6, RW=8 wraparound rings + credit flow control) unchanged from R6.

constexpr int TT = 512;
constexpr int BB = 1024;
constexpr int HH = 49;
constexpr int GG = 196;

constexpr int RW = 8;                               // ring window (blocks, pow2)
constexpr size_t R_SAMP      = (size_t)RW * 416;    // floats per sample
constexpr size_t R_LAYER     = 1024ull * R_SAMP;    // floats per ring (layer)
constexpr size_t RING_FLOATS = 6ull * R_LAYER;      // rings for layers 0..5
constexpr size_t FLAG_INTS   = 12ull * 64 * 32;     // [0..5]=prod, [6..11]=cons
constexpr size_t WS_NEEDED   = RING_FLOATS * 4 + FLAG_INTS * 4;   // ~82 MB

typedef __attribute__((ext_vector_type(8))) short short8;
typedef __attribute__((ext_vector_type(4))) short short4v;
typedef __attribute__((ext_vector_type(4))) float f32x4;
typedef unsigned long long u64;

__device__ __forceinline__ float sigmoidf_(float x) {
    return 1.0f / (1.0f + __expf(-x));
}
__device__ __forceinline__ float tanhf_(float x) {
    return 1.0f - 2.0f / (1.0f + __expf(2.0f * x));
}

__device__ __forceinline__ void bf16split(float x, short& hi, short& lo) {
    unsigned u = __float_as_uint(x);
    unsigned r = u + 0x7FFFu + ((u >> 16) & 1u);
    hi = (short)(r >> 16);
    float fhi = __uint_as_float(r & 0xFFFF0000u);
    float rem = x - fhi;
    unsigned u2 = __float_as_uint(rem);
    unsigned r2 = u2 + 0x7FFFu + ((u2 >> 16) & 1u);
    lo = (short)(r2 >> 16);
}

// fragment-order element address (2B units) of A[m][k], m<16, k<128
__device__ __forceinline__ int addr2B(int m, int k) {
    return (k >> 5) * 512 + ((k >> 3) & 3) * 128 + m * 8 + (k & 7);
}

// ring access: relaxed agent-scope atomics -> sc1 (MALL-coherent), no fences
__device__ __forceinline__ u64 ring_ld8(const float* p) {
    return __hip_atomic_load((u64*)p, __ATOMIC_RELAXED, __HIP_MEMORY_SCOPE_AGENT);
}
__device__ __forceinline__ void ring_st(float* p, float v) {
    __hip_atomic_store(p, v, __ATOMIC_RELAXED, __HIP_MEMORY_SCOPE_AGENT);
}

#define WGBAR() asm volatile("s_waitcnt lgkmcnt(0)\n\ts_barrier" ::: "memory")
#define VMDRAIN() asm volatile("s_waitcnt vmcnt(0)" ::: "memory")

__global__ void zero_flags(int* f, int n) {
    int i = blockIdx.x * 256 + threadIdx.x;
    if (i < n) f[i] = 0;
}

__global__ __launch_bounds__(448, 4)
void lstm_pipe(const float* __restrict__ xin,    // [B,T,7]
               float* __restrict__ ring,         // [6][1024][RW][8][52]
               int* __restrict__ flags,          // [12][64][32]
               const float* __restrict__ Wih0,   // [196,7]
               const float* __restrict__ Wihr,   // [6,196,49]
               const float* __restrict__ Whh,    // [7,196,49]
               const float* __restrict__ bih,    // [7,196]
               const float* __restrict__ bhh,    // [7,196]
               const float* __restrict__ fcw,    // [7,49]
               const float* __restrict__ fcb,    // [7]
               float* __restrict__ outp)         // [B,T,7]
{
    __shared__ __align__(16) short Ahi[2][2048];     // [parity][frag order]
    __shared__ __align__(16) short Alo[2][2048];
    __shared__ __align__(16) float preT[13 * 16 * 20];
    __shared__ __align__(16) float h_sh[2][16][52];  // layer-6 h, by parity
    __shared__ __align__(16) float w7[7][52];        // fc weights (padded 0)
    __shared__ float bsh[8];

    const int tid  = threadIdx.x;
    const int wave = tid >> 6;
    const int lane = tid & 63;
    const int quad = lane >> 4;
    const int lrow = lane & 15;

    const int l   = blockIdx.x >> 6;             // layer 0..6
    const int grp = blockIdx.x & 63;             // sample group
    const int b0  = grp << 4;                    // 16 samples

    const int DIN  = (l == 0) ? 7 : 49;
    const int KSRT = (l == 0) ? 2 : 4;           // active k-steps
    const float* Wih = (l == 0) ? Wih0 : (Wihr + (size_t)(l - 1) * GG * HH);
    const float* Whl = Whh + (size_t)l * GG * HH;
    const float* bi  = bih + (size_t)l * GG;
    const float* bh  = bhh + (size_t)l * GG;

    const int lm1 = (l > 0) ? (l - 1) : 0;
    const int lp  = (l < 6) ? l : 0;
    const float* rin  = ring + (size_t)lm1 * R_LAYER;
    float*       rout = ring + (size_t)lp  * R_LAYER;
    int* flag_in   = flags + (size_t)lm1 * 2048 + (size_t)grp * 32;       // prod(ring l-1)
    int* cons_sig  = flags + (size_t)(6 + lm1) * 2048 + (size_t)grp * 32; // we consumed l-1
    int* flag_out  = flags + (size_t)lp * 2048 + (size_t)grp * 32;        // prod(ring l)
    int* cons_poll = flags + (size_t)(6 + lp) * 2048 + (size_t)grp * 32;  // consumer of l
    const bool wr = (l < 6);                     // layer 6 has no output ring

    const int ntiles = (wave < 6) ? 2 : 1;
    const int tA = (wave < 6) ? wave : 12;
    const int tB = wave + 6;                     // valid if wave<6

    // ---- B fragments (hi/lo) + bias in VGPRs -----------------------------
    short8 BH[2][4], BL[2][4];
    float  biasv[2];
    #pragma unroll
    for (int ti = 0; ti < 2; ++ti) {
        const int  nt    = ti ? tB : tA;
        const bool valid = (ti < ntiles) && (nt < 13);
        const int  np    = nt * 16 + lrow;       // permuted row r' = 4j+gate
        const int  j     = np >> 2;
        const int  g     = np & 3;
        const bool jb    = valid && (j < HH);
        biasv[ti] = jb ? (bi[g * HH + j] + bh[g * HH + j]) : 0.0f;
        #pragma unroll
        for (int ks = 0; ks < 4; ++ks) {
            #pragma unroll
            for (int jj = 0; jj < 8; ++jj) {
                const int k = ks * 32 + quad * 8 + jj;
                float wv = 0.0f;
                if (jb) {
                    const int r = g * HH + j;
                    if (k < HH)                       wv = Whl[r * HH + k];
                    else if (k >= 52 && k < 52 + DIN) wv = Wih[r * DIN + (k - 52)];
                }
                short h_, l_;
                bf16split(wv, h_, l_);
                BH[ti][ks][jj] = h_;
                BL[ti][ks][jj] = l_;
            }
        }
    }

    // ---- EW cells: lane owns (tile, j = 4*nt+quad, sample s = lrow) ------
    const int  j0 = 4 * tA + quad;
    const int  j1 = 4 * tB + quad;
    const bool v0 = (j0 < HH);                   // false only wave6 quads 1..3
    const bool v1 = (wave < 6);                  // then j1<=47<49
    const int  ah0 = addr2B(lrow, j0);
    const int  ah1 = addr2B(lrow, j1);
    float* rc0 = rout + (size_t)(b0 + lrow) * R_SAMP + j0;
    float* rc1 = rout + (size_t)(b0 + lrow) * R_SAMP + j1;
    float cc0 = 0.0f, cc1 = 0.0f;

    // ---- loader role -----------------------------------------------------
    bool is_ld;
    int  ld_m, ld_kx, a_st;
    const float* gb;                             // per-lane load base
    if (l == 0) {
        is_ld = (tid < 112);                     // 16 samples x 7 cols
        ld_m  = tid / 7;
        ld_kx = tid - ld_m * 7;
        a_st  = addr2B(ld_m & 15, 52 + ld_kx);
        gb    = xin + ((size_t)(b0 + (ld_m & 15)) * TT) * 7 + ld_kx;
    } else {
        is_ld = (tid < 208);                     // 16 samples x 13 quads
        ld_m  = tid / 13;
        ld_kx = tid - ld_m * 13;                 // k-quad
        a_st  = addr2B(ld_m & 15, 52 + 4 * ld_kx);
        gb    = rin + (size_t)(b0 + (ld_m & 15)) * R_SAMP + 4 * ld_kx;
    }

    // ---- init ------------------------------------------------------------
    for (int i = tid; i < 2048; i += 448) {
        ((unsigned*)Ahi)[i] = 0u;
        ((unsigned*)Alo)[i] = 0u;
    }
    if (l == 6) {
        for (int i = tid; i < 2 * 16 * 52; i += 448) ((float*)h_sh)[i] = 0.0f;
        for (int i = tid; i < 7 * 52; i += 448) {
            const int o = i / 52, k = i - o * 52;
            w7[o][k] = (k < HH) ? fcw[o * HH + k] : 0.0f;
        }
        if (tid < 7) bsh[tid] = fcb[tid];
    }
    __syncthreads();

    if (l > 0) {                                 // wait for input block 0
        if (tid == 0) {
            while (__hip_atomic_load(flag_in, __ATOMIC_RELAXED,
                                     __HIP_MEMORY_SCOPE_AGENT) < 1)
                __builtin_amdgcn_s_sleep(2);
        }
        __syncthreads();
    }

    // prologue: load + stage x_0 -> A[0]
    if (is_ld) {
        if (l == 0) {
            short h_, l_;
            bf16split(gb[0], h_, l_);
            Ahi[0][a_st] = h_; Alo[0][a_st] = l_;
        } else {
            const u64 a = ring_ld8(gb);
            const u64 b = ring_ld8(gb + 2);
            short h0,l0_,h1,l1_,h2,l2_,h3,l3_;
            bf16split(__uint_as_float((unsigned)a),         h0, l0_);
            bf16split(__uint_as_float((unsigned)(a >> 32)), h1, l1_);
            bf16split(__uint_as_float((unsigned)b),         h2, l2_);
            bf16split(__uint_as_float((unsigned)(b >> 32)), h3, l3_);
            short4v vh = {h0,h1,h2,h3}, vl = {l0_,l1_,l2_,l3_};
            *(short4v*)&Ahi[0][a_st] = vh;
            *(short4v*)&Alo[0][a_st] = vl;
        }
    }
    __syncthreads();

    // ---- scan ------------------------------------------------------------
    for (int t = 0; t < TT; ++t) {
        const int p  = t & 1;
        const int tb = t & 7;

        // A: producer chores — drain block k-1 stores (tb2), publish (tb3).
        // Cross-step gap: the WGBAR between tb2 and tb3 means all waves'
        // drains happened before tid0's store.
        if (wr && tb == 2) VMDRAIN();
        if (wr && tb == 3 && (t >> 3) >= 1 && tid == 0)
            __hip_atomic_store(flag_out, t >> 3, __ATOMIC_RELAXED,
                               __HIP_MEMORY_SCOPE_AGENT);

        // B1: consumer gate — before the tb7 step issues the first load of
        // block m+1 (x_{8m+8}), require it published.
        if (l > 0 && tb == 6 && (t + 2) < TT) {
            if (tid == 0) {
                const int want = ((t + 2) >> 3) + 1;
                while (__hip_atomic_load(flag_in, __ATOMIC_RELAXED,
                                         __HIP_MEMORY_SCOPE_AGENT) < want)
                    __builtin_amdgcn_s_sleep(2);
            }
            __syncthreads();
        }
        // B2: consumer signal — all block-m loads were issued by step 8m+6;
        // drain them, then publish "blocks <= m consumed".
        if (l > 0 && tb == 7) {
            VMDRAIN();
            __syncthreads();
            if (tid == 0)
                __hip_atomic_store(cons_sig, (t >> 3) + 1, __ATOMIC_RELAXED,
                                   __HIP_MEMORY_SCOPE_AGENT);
        }

        // D: issue load of x_{t+1} (staged at bottom of this step; the
        // MFMA+EW phases hide the ~1000cy L3 latency)
        const bool ldnow = is_ld && (t + 1) < TT;
        float xs = 0.0f;
        u64 xa = 0, xb = 0;
        if (ldnow) {
            if (l == 0) {
                xs = gb[(size_t)(t + 1) * 7];
            } else {
                const int offn = (((t + 1) >> 3) & (RW - 1)) * 416
                               + ((t + 1) & 7) * 52;
                xa = ring_ld8(gb + offn);
                xb = ring_ld8(gb + offn + 2);
            }
        }

        // E: A fragments (parity p), conflict-free b128 + MFMA + preT
        short8 AH[4], AL[4];
        #pragma unroll
        for (int ks = 0; ks < 4; ++ks) {
            if (ks < KSRT) {
                AH[ks] = *(const short8*)&Ahi[p][ks * 512 + lane * 8];
                AL[ks] = *(const short8*)&Alo[p][ks * 512 + lane * 8];
            }
        }

        f32x4 C0 = {biasv[0], biasv[0], biasv[0], biasv[0]};
        #pragma unroll
        for (int ks = 0; ks < 4; ++ks) {
            if (ks < KSRT) {
                C0 = __builtin_amdgcn_mfma_f32_16x16x32_bf16(AH[ks], BH[0][ks], C0, 0, 0, 0);
                C0 = __builtin_amdgcn_mfma_f32_16x16x32_bf16(AL[ks], BH[0][ks], C0, 0, 0, 0);
                C0 = __builtin_amdgcn_mfma_f32_16x16x32_bf16(AH[ks], BL[0][ks], C0, 0, 0, 0);
            }
        }
        #pragma unroll
        for (int r = 0; r < 4; ++r)
            preT[(tA * 16 + 4 * quad + r) * 20 + lrow] = C0[r];

        if (wave < 6) {
            f32x4 C1 = {biasv[1], biasv[1], biasv[1], biasv[1]};
            #pragma unroll
            for (int ks = 0; ks < 4; ++ks) {
                if (ks < KSRT) {
                    C1 = __builtin_amdgcn_mfma_f32_16x16x32_bf16(AH[ks], BH[1][ks], C1, 0, 0, 0);
                    C1 = __builtin_amdgcn_mfma_f32_16x16x32_bf16(AL[ks], BH[1][ks], C1, 0, 0, 0);
                    C1 = __builtin_amdgcn_mfma_f32_16x16x32_bf16(AH[ks], BL[1][ks], C1, 0, 0, 0);
                }
            }
            #pragma unroll
            for (int r = 0; r < 4; ++r)
                preT[(tB * 16 + 4 * quad + r) * 20 + lrow] = C1[r];
        }

        // F: fused FC (layer 6): consume h_{t-1} from h_sh[p]
        if (l == 6 && t > 0 && tid < 112) {
            const int s = tid / 7;
            const int o = tid - s * 7;
            const float* hr = h_sh[p][s];
            float acc = bsh[o];
            #pragma unroll
            for (int k = 0; k < 52; k += 4) {
                const f32x4 hv4 = *(const f32x4*)&hr[k];
                const f32x4 wv4 = *(const f32x4*)&w7[o][k];
                acc = fmaf(hv4.x, wv4.x, acc);
                acc = fmaf(hv4.y, wv4.y, acc);
                acc = fmaf(hv4.z, wv4.z, acc);
                acc = fmaf(hv4.w, wv4.w, acc);
            }
            outp[((size_t)(b0 + s) * TT + (t - 1)) * 7 + o] = acc;
        }

        // G: EW (wave-local preT RAW; lgkm in-wave) + ring/h_sh stores
        const int offc = ((t >> 3) & (RW - 1)) * 416 + tb * 52;
        if (v0) {
            const f32x4 gt = *(const f32x4*)&preT[(tA * 16 + lrow) * 20 + 4 * quad];
            const float i_ = sigmoidf_(gt.x);
            const float f_ = sigmoidf_(gt.y);
            const float g_ = tanhf_(gt.z);
            const float o_ = sigmoidf_(gt.w);
            cc0 = f_ * cc0 + i_ * g_;
            const float hv = o_ * tanhf_(cc0);
            short hh, hl;
            bf16split(hv, hh, hl);
            Ahi[p ^ 1][ah0] = hh;
            Alo[p ^ 1][ah0] = hl;
            if (wr) ring_st(rc0 + offc, hv);
            else    h_sh[p ^ 1][lrow][j0] = hv;
        } else if (wr) {
            ring_st(rc0 + offc, 0.0f);           // pad cols 49..51: NaN-free
        }
        if (v1) {
            const f32x4 gt = *(const f32x4*)&preT[(tB * 16 + lrow) * 20 + 4 * quad];
            const float i_ = sigmoidf_(gt.x);
            const float f_ = sigmoidf_(gt.y);
            const float g_ = tanhf_(gt.z);
            const float o_ = sigmoidf_(gt.w);
            cc1 = f_ * cc1 + i_ * g_;
            const float hv = o_ * tanhf_(cc1);
            short hh, hl;
            bf16split(hv, hh, hl);
            Ahi[p ^ 1][ah1] = hh;
            Alo[p ^ 1][ah1] = hl;
            if (wr) ring_st(rc1 + offc, hv);
            else    h_sh[p ^ 1][lrow][j1] = hv;
        }

        // C: stage x_{t+1} -> A[p^1] (compiler waits the D-phase load here)
        if (ldnow) {
            if (l == 0) {
                short h_, l_;
                bf16split(xs, h_, l_);
                Ahi[p ^ 1][a_st] = h_; Alo[p ^ 1][a_st] = l_;
            } else {
                short h0,l0_,h1,l1_,h2,l2_,h3,l3_;
                bf16split(__uint_as_float((unsigned)xa),         h0, l0_);
                bf16split(__uint_as_float((unsigned)(xa >> 32)), h1, l1_);
                bf16split(__uint_as_float((unsigned)xb),         h2, l2_);
                bf16split(__uint_as_float((unsigned)(xb >> 32)), h3, l3_);
                short4v vh = {h0,h1,h2,h3}, vl = {l0_,l1_,l2_,l3_};
                *(short4v*)&Ahi[p ^ 1][a_st] = vh;
                *(short4v*)&Alo[p ^ 1][a_st] = vl;
            }
        }

        // H: producer wrap gate — before entering block k=(t+1)>>3, slot
        // k%RW must be consumed (cons >= k-RW+1). tid0 polls; the step-end
        // barrier holds everyone else; block-k stores come after it.
        if (wr && tb == 7 && (t + 1) < TT && ((t + 1) >> 3) >= RW && tid == 0) {
            const int need = ((t + 1) >> 3) - RW + 1;
            while (__hip_atomic_load(cons_poll, __ATOMIC_RELAXED,
                                     __HIP_MEMORY_SCOPE_AGENT) < need)
                __builtin_amdgcn_s_sleep(2);
        }

        WGBAR();   // lgkm-only: A[p^1] + preT + h_sh reuse safe; vm stores
                   // stay in flight (drained only at tb2/tb7 chores)
    }

    // fused FC epilogue: h_511 was written to h_sh[0] (t=511, p=1)
    if (l == 6 && tid < 112) {
        const int s = tid / 7;
        const int o = tid - s * 7;
        const float* hr = h_sh[0][s];
        float acc = bsh[o];
        #pragma unroll
        for (int k = 0; k < 52; k += 4) {
            const f32x4 hv4 = *(const f32x4*)&hr[k];
            const f32x4 wv4 = *(const f32x4*)&w7[o][k];
            acc = fmaf(hv4.x, wv4.x, acc);
            acc = fmaf(hv4.y, wv4.y, acc);
            acc = fmaf(hv4.z, wv4.z, acc);
            acc = fmaf(hv4.w, wv4.w, acc);
        }
        outp[((size_t)(b0 + s) * TT + 511) * 7 + o] = acc;
    }

    // epilogue: publish completion (covers blocks 56..63)
    if (wr) {
        VMDRAIN();
        __syncthreads();
        if (tid == 0)
            __hip_atomic_store(flag_out, 64, __ATOMIC_RELAXED,
                               __HIP_MEMORY_SCOPE_AGENT);
    }
}

// ======================= fallback path (R4, per-layer) ======================

template<int DIN>
__global__ __launch_bounds__(448)
void lstm_fb(const float* xin, float* hout,
             const float* __restrict__ Wih, const float* __restrict__ Whh,
             const float* __restrict__ bihp, const float* __restrict__ bhhp)
{
    constexpr int XO = 52;
    constexpr int KTOT = XO + DIN;
    constexpr int KSTEPS = (KTOT + 31) / 32;
    __shared__ short Ahi[2][KSTEPS * 512];
    __shared__ short Alo[2][KSTEPS * 512];
    __shared__ float preT[13 * 64];

    const int tid = threadIdx.x, wave = tid >> 6, lane = tid & 63;
    const int quad = lane >> 4, lrow = lane & 15;
    const int b0 = blockIdx.x * 4;
    const int ntiles = (wave < 6) ? 2 : 1;
    const int tileA = (wave < 6) ? wave : 12;
    const int tileB = wave + 6;

    short8 BH[2][KSTEPS], BL[2][KSTEPS];
    float biasv[2];
    #pragma unroll
    for (int ti = 0; ti < 2; ++ti) {
        const int nt = ti ? tileB : tileA;
        const bool valid = (ti < ntiles);
        const int np = nt * 16 + lrow, j = np >> 2, g = np & 3;
        biasv[ti] = (valid && j < HH) ? (bihp[g*HH+j] + bhhp[g*HH+j]) : 0.0f;
        #pragma unroll
        for (int ks = 0; ks < KSTEPS; ++ks)
            #pragma unroll
            for (int jj = 0; jj < 8; ++jj) {
                const int k = ks * 32 + quad * 8 + jj;
                float wv = 0.0f;
                if (valid && j < HH) {
                    const int r = g * HH + j;
                    if (k < HH) wv = Whh[r * HH + k];
                    else if (k >= XO && k < KTOT) wv = Wih[r * DIN + (k - XO)];
                }
                short h_, l_; bf16split(wv, h_, l_);
                BH[ti][ks][jj] = h_; BL[ti][ks][jj] = l_;
            }
    }

    const int ec = lane & 15, ew_jj = ec >> 2, ew_m = ec & 3, ew_ti = lane >> 4;
    const bool is_ew = (lane < 32) && (ew_ti < ntiles);
    const int ew_nt = ew_ti ? tileB : tileA;
    const int ew_j = 4 * ew_nt + ew_jj;
    const bool ew_ok = is_ew && (ew_j < HH);
    const int pa0 = (ew_nt*16 + 4*ew_jj + 0)*4 + ew_m;
    const int pa1 = (ew_nt*16 + 4*ew_jj + 1)*4 + ew_m;
    const int pa2 = (ew_nt*16 + 4*ew_jj + 2)*4 + ew_m;
    const int pa3 = (ew_nt*16 + 4*ew_jj + 3)*4 + ew_m;
    const int ew_ah = addr2B(ew_m, ew_j);
    float cc = 0.0f;

    const int lx = tid;
    const bool is_loader = (lx < 4 * DIN);
    const int ld_m = is_loader ? (lx & 3) : 0, ld_k = is_loader ? (lx >> 2) : 0;
    const int xaddr = addr2B(ld_m, XO + ld_k);
    const size_t xbase = ((size_t)(b0 + ld_m) * TT) * DIN + ld_k;
    float* houtp = hout + ((size_t)(b0 + ew_m) * TT) * HH + (ew_ok ? ew_j : 0);

    for (int i = tid; i < KSTEPS * 512; i += 448) {
        ((unsigned*)Ahi)[i] = 0u; ((unsigned*)Alo)[i] = 0u;
    }
    __syncthreads();
    if (is_loader) {
        short h_, l_; bf16split(xin[xbase], h_, l_);
        Ahi[0][xaddr] = h_; Alo[0][xaddr] = l_;
    }
    __syncthreads();

    for (int t = 0; t < TT; ++t) {
        const int p = t & 1;
        float xnext = 0.0f;
        if (is_loader && (t + 1 < TT)) xnext = xin[xbase + (size_t)(t+1) * DIN];

        short8 AH[KSTEPS], AL[KSTEPS];
        #pragma unroll
        for (int ks = 0; ks < KSTEPS; ++ks) {
            AH[ks] = *(const short8*)&Ahi[p][ks * 512 + lane * 8];
            AL[ks] = *(const short8*)&Alo[p][ks * 512 + lane * 8];
        }
        #pragma unroll
        for (int ti = 0; ti < 2; ++ti) {
            f32x4 C = {biasv[ti], biasv[ti], biasv[ti], biasv[ti]};
            #pragma unroll
            for (int ks = 0; ks < KSTEPS; ++ks) {
                C = __builtin_amdgcn_mfma_f32_16x16x32_bf16(AH[ks], BH[ti][ks], C, 0, 0, 0);
                C = __builtin_amdgcn_mfma_f32_16x16x32_bf16(AL[ks], BH[ti][ks], C, 0, 0, 0);
                C = __builtin_amdgcn_mfma_f32_16x16x32_bf16(AH[ks], BL[ti][ks], C, 0, 0, 0);
            }
            if (ti < ntiles && lane < 16) {
                const int nt = ti ? tileB : tileA;
                *(f32x4*)&preT[(nt * 16 + lrow) * 4] = C;
            }
        }
        if (is_ew) {
            const float i_ = sigmoidf_(preT[pa0]);
            const float f_ = sigmoidf_(preT[pa1]);
            const float g_ = tanhf_(preT[pa2]);
            const float o_ = sigmoidf_(preT[pa3]);
            cc = f_ * cc + i_ * g_;
            const float hv = o_ * tanhf_(cc);
            if (ew_ok) {
                short hh, hl; bf16split(hv, hh, hl);
                Ahi[p ^ 1][ew_ah] = hh; Alo[p ^ 1][ew_ah] = hl;
                houtp[(size_t)t * HH] = hv;
            }
        }
        if (is_loader && (t + 1 < TT)) {
            short h_, l_; bf16split(xnext, h_, l_);
            Ahi[p ^ 1][xaddr] = h_; Alo[p ^ 1][xaddr] = l_;
        }
        __syncthreads();
    }
}

__global__ __launch_bounds__(256)
void fc_fb(const float* __restrict__ hbuf, const float* __restrict__ fcw,
           const float* __restrict__ fcb, float* __restrict__ outp)
{
    constexpr int HP = 52;
    __shared__ float w[7][HP];
    __shared__ float bsh[8];
    const int tid = threadIdx.x;
    for (int i = tid; i < 7 * HP; i += 256) {
        const int o = i / HP, k = i - o * HP;
        w[o][k] = (k < HH) ? fcw[o * HH + k] : 0.0f;
    }
    if (tid < 7) bsh[tid] = fcb[tid];
    __syncthreads();
    const size_t i = (size_t)blockIdx.x * 256 + tid;
    float acc[7];
    #pragma unroll
    for (int j = 0; j < 7; ++j) acc[j] = bsh[j];
    const float* hp = hbuf + i * HH;
    #pragma unroll
    for (int k = 0; k < HH; ++k) {
        const float hv = hp[k];
        #pragma unroll
        for (int j = 0; j < 7; ++j) acc[j] = fmaf(hv, w[j][k], acc[j]);
    }
    #pragma unroll
    for (int j = 0; j < 7; ++j) outp[i * 7 + j] = acc[j];
}

extern "C" void kernel_launch(void* const* d_in, const int* in_sizes, int n_in,
                              void* d_out, int out_size, void* d_ws, size_t ws_size,
                              hipStream_t stream)
{
    const float* x    = (const float*)d_in[0];
    const float* Wih0 = (const float*)d_in[1];
    const float* Wihr = (const float*)d_in[2];
    const float* Whh  = (const float*)d_in[3];
    const float* bih  = (const float*)d_in[4];
    const float* bhh  = (const float*)d_in[5];
    const float* fcw  = (const float*)d_in[6];
    const float* fcb  = (const float*)d_in[7];
    float* outp = (float*)d_out;

    if (ws_size >= WS_NEEDED) {
        float* ring  = (float*)d_ws;
        int*   flags = (int*)((char*)d_ws + RING_FLOATS * 4);
        zero_flags<<<(int)((FLAG_INTS + 255) / 256), 256, 0, stream>>>(
            flags, (int)FLAG_INTS);
        lstm_pipe<<<448, 448, 0, stream>>>(x, ring, flags, Wih0, Wihr,
                                           Whh, bih, bhh, fcw, fcb, outp);
    } else {
        float* hbuf = (float*)d_ws;   // [B,T,49]
        lstm_fb<7><<<BB / 4, 448, 0, stream>>>(x, hbuf, Wih0, Whh, bih, bhh);
        for (int l = 1; l < 7; ++l) {
            lstm_fb<49><<<BB / 4, 448, 0, stream>>>(
                hbuf, hbuf,
                Wihr + (size_t)(l - 1) * GG * HH,
                Whh  + (size_t)l * GG * HH,
                bih  + (size_t)l * GG,
                bhh  + (size_t)l * GG);
        }
        fc_fb<<<(BB * TT) / 256, 256, 0, stream>>>(hbuf, fcw, fcb, outp);
    }
}

// Round 4
// 2451.185 us; speedup vs baseline: 2.9283x; 1.2206x over previous
//
#include <hip/hip_runtime.h>
#include <math.h>

// LSTM: L=7, H=49, B=1024, T=512, I=7, O=7. fp32 in/out.
//
// Round 9: fix R8's consumer-loader width bug (13 of 49 columns loaded).
//  - R8 post-mortem: FAILED absmax 6.9e-2. The transposed ring slot
//    [52 cols][16 samps] needs 52 cols staged per step, but the loader
//    assigned 1 col/lane with jc=tid>>4 in [0,13) -> cols 13..48 of every
//    layer handoff stayed zero. Deterministic algorithmic bug, not a race.
//  - Fix: 208 loader lanes each load 4 cols at stride 16 floats (cols
//    4jc..4jc+3; each dword coalesces 16 lanes over one 64B line). Cols
//    48..51 ride along: producer pad lanes store exact 0.0 and their B
//    rows are zero. Prefetch regs back to float4 fA/fB (R7-proven), and
//    staging is the R7-proven short4v path ((52+4jc)&7 in {0,4} so each
//    4-col group is contiguous+aligned in fragment order).
//  - R8's store-side fixes kept verbatim: [8][52][16] ring slot (one
//    coalesced 256B wave-store per tile, full lines, MALL-clean); no
//    __syncthreads in the loop (B1 gate = lgkm-only WGBAR; B2 signal
//    drain-free - each loader's block-m loads are register-consumed at C
//    of step 8m+6, barrier-ordered before the tb==7 signal); pads
//    self-compute exact zero so tile-A EW/store is unconditional; all
//    flag polls/stores on tid 384 (wave 6 lane 0); relaxed agent-scope
//    atomics for ring+flags (MALL-coherent, zero cache-maintenance).
//  - Unchanged core: MFMA 16x16x32 bf16 3-pass hi/lo, 13 N-tiles gate-
//    interleaved, bias via MFMA C-init, wave-local preT, parity A planes,
//    RW=8 credit flow control, fused FC in layer 6, R4 fallback path.

constexpr int TT = 512;
constexpr int BB = 1024;
constexpr int HH = 49;
constexpr int GG = 196;

constexpr int RW = 8;                         // ring window (blocks, pow2)
constexpr int SLOT_STEP = 832;                // 52 cols x 16 samps (floats)
constexpr int SLOT_BLK  = 8 * SLOT_STEP;      // 6656 floats per block
constexpr size_t R_GRP       = (size_t)RW * SLOT_BLK;   // per (layer,grp)
constexpr size_t R_LAYER     = 64ull * R_GRP;
constexpr size_t RING_FLOATS = 6ull * R_LAYER;          // ~81.8 MB
constexpr size_t FLAG_INTS   = 12ull * 64 * 32;         // [0..5]prod [6..11]cons
constexpr size_t WS_NEEDED   = RING_FLOATS * 4 + FLAG_INTS * 4;

typedef __attribute__((ext_vector_type(8))) short short8;
typedef __attribute__((ext_vector_type(4))) short short4v;
typedef __attribute__((ext_vector_type(4))) float f32x4;

__device__ __forceinline__ float sigmoidf_(float x) {
    return 1.0f / (1.0f + __expf(-x));
}
__device__ __forceinline__ float tanhf_(float x) {
    return 1.0f - 2.0f / (1.0f + __expf(2.0f * x));
}

__device__ __forceinline__ void bf16split(float x, short& hi, short& lo) {
    unsigned u = __float_as_uint(x);
    unsigned r = u + 0x7FFFu + ((u >> 16) & 1u);
    hi = (short)(r >> 16);
    float fhi = __uint_as_float(r & 0xFFFF0000u);
    float rem = x - fhi;
    unsigned u2 = __float_as_uint(rem);
    unsigned r2 = u2 + 0x7FFFu + ((u2 >> 16) & 1u);
    lo = (short)(r2 >> 16);
}

// fragment-order element address (2B units) of A[m][k], m<16, k<128
__device__ __forceinline__ int addr2B(int m, int k) {
    return (k >> 5) * 512 + ((k >> 3) & 3) * 128 + m * 8 + (k & 7);
}

// ring/flag access: relaxed agent-scope atomics (MALL-coherent), no fences
__device__ __forceinline__ float ring_ldf(const float* p) {
    return __hip_atomic_load(p, __ATOMIC_RELAXED, __HIP_MEMORY_SCOPE_AGENT);
}
__device__ __forceinline__ void ring_st(float* p, float v) {
    __hip_atomic_store(p, v, __ATOMIC_RELAXED, __HIP_MEMORY_SCOPE_AGENT);
}
__device__ __forceinline__ int flag_ld(const int* p) {
    return __hip_atomic_load(p, __ATOMIC_RELAXED, __HIP_MEMORY_SCOPE_AGENT);
}
__device__ __forceinline__ void flag_st(int* p, int v) {
    __hip_atomic_store(p, v, __ATOMIC_RELAXED, __HIP_MEMORY_SCOPE_AGENT);
}

#define WGBAR() asm volatile("s_waitcnt lgkmcnt(0)\n\ts_barrier" ::: "memory")
#define VMDRAIN() asm volatile("s_waitcnt vmcnt(0)" ::: "memory")

__global__ void zero_flags(int* f, int n) {
    int i = blockIdx.x * 256 + threadIdx.x;
    if (i < n) f[i] = 0;
}

__global__ __launch_bounds__(448, 4)
void lstm_pipe(const float* __restrict__ xin,    // [B,T,7]
               float* __restrict__ ring,         // [6][64][RW][8][52][16]
               int* __restrict__ flags,          // [12][64][32]
               const float* __restrict__ Wih0,   // [196,7]
               const float* __restrict__ Wihr,   // [6,196,49]
               const float* __restrict__ Whh,    // [7,196,49]
               const float* __restrict__ bih,    // [7,196]
               const float* __restrict__ bhh,    // [7,196]
               const float* __restrict__ fcw,    // [7,49]
               const float* __restrict__ fcb,    // [7]
               float* __restrict__ outp)         // [B,T,7]
{
    __shared__ __align__(16) short Ahi[2][2048];     // [parity][frag order]
    __shared__ __align__(16) short Alo[2][2048];
    __shared__ __align__(16) float preT[13 * 16 * 20];
    __shared__ __align__(16) float h_sh[2][16][52];  // layer-6 h, by parity
    __shared__ __align__(16) float w7[7][52];        // fc weights (padded 0)
    __shared__ float bsh[8];

    const int tid  = threadIdx.x;
    const int wave = tid >> 6;
    const int lane = tid & 63;
    const int quad = lane >> 4;
    const int lrow = lane & 15;
    const bool actor = (tid == 384);             // wave 6 lane 0

    const int l   = blockIdx.x >> 6;             // layer 0..6
    const int grp = blockIdx.x & 63;             // sample group
    const int b0  = grp << 4;                    // 16 samples

    const int DIN  = (l == 0) ? 7 : 49;
    const int KSRT = (l == 0) ? 2 : 4;           // active k-steps
    const float* Wih = (l == 0) ? Wih0 : (Wihr + (size_t)(l - 1) * GG * HH);
    const float* Whl = Whh + (size_t)l * GG * HH;
    const float* bi  = bih + (size_t)l * GG;
    const float* bh  = bhh + (size_t)l * GG;

    const int lm1 = (l > 0) ? (l - 1) : 0;
    const int lp  = (l < 6) ? l : 0;
    const float* rin_g = ring + (size_t)lm1 * R_LAYER + (size_t)grp * R_GRP;
    float*       rout_g = ring + (size_t)lp * R_LAYER + (size_t)grp * R_GRP;
    int* flag_in   = flags + (size_t)lm1 * 2048 + (size_t)grp * 32;       // prod(l-1)
    int* cons_sig  = flags + (size_t)(6 + lm1) * 2048 + (size_t)grp * 32; // we ate l-1
    int* flag_out  = flags + (size_t)lp * 2048 + (size_t)grp * 32;        // prod(l)
    int* cons_poll = flags + (size_t)(6 + lp) * 2048 + (size_t)grp * 32;  // eater of l
    const bool wr = (l < 6);                     // layer 6 has no output ring

    const int ntiles = (wave < 6) ? 2 : 1;
    const int tA = (wave < 6) ? wave : 12;
    const int tB = wave + 6;                     // valid if wave<6

    // ---- B fragments (hi/lo) + bias in VGPRs -----------------------------
    short8 BH[2][4], BL[2][4];
    float  biasv[2];
    #pragma unroll
    for (int ti = 0; ti < 2; ++ti) {
        const int  nt    = ti ? tB : tA;
        const bool valid = (ti < ntiles) && (nt < 13);
        const int  np    = nt * 16 + lrow;       // permuted row r' = 4j+gate
        const int  j     = np >> 2;
        const int  g     = np & 3;
        const bool jb    = valid && (j < HH);
        biasv[ti] = jb ? (bi[g * HH + j] + bh[g * HH + j]) : 0.0f;
        #pragma unroll
        for (int ks = 0; ks < 4; ++ks) {
            #pragma unroll
            for (int jj = 0; jj < 8; ++jj) {
                const int k = ks * 32 + quad * 8 + jj;
                float wv = 0.0f;
                if (jb) {
                    const int r = g * HH + j;
                    if (k < HH)                       wv = Whl[r * HH + k];
                    else if (k >= 52 && k < 52 + DIN) wv = Wih[r * DIN + (k - 52)];
                }
                short h_, l_;
                bf16split(wv, h_, l_);
                BH[ti][ks][jj] = h_;
                BL[ti][ks][jj] = l_;
            }
        }
    }

    // ---- EW cells: lane owns (tile, j = 4*nt+quad, sample s = lrow) ------
    const int  j0 = 4 * tA + quad;               // <=51 (pads 49..51 compute 0)
    const int  j1 = 4 * tB + quad;
    const bool v1 = (wave < 6);                  // then j1<=47<49
    const int  ah0 = addr2B(lrow, j0);
    const int  ah1 = addr2B(lrow, j1);
    // coalesced ring store base: slot layout [col][samp] -> tile*64 + lane
    float* rc0 = rout_g + tA * 64 + lane;
    float* rc1 = rout_g + tB * 64 + lane;
    float cc0 = 0.0f, cc1 = 0.0f;

    // ---- loader role -----------------------------------------------------
    bool is_ld;
    int  a_st;
    const float* gb;                             // per-lane load base
    if (l == 0) {
        is_ld = (tid < 112);                     // 16 samples x 7 cols
        const int m  = tid / 7;
        const int kx = tid - m * 7;
        a_st = addr2B(m & 15, 52 + kx);
        gb   = xin + ((size_t)(b0 + (m & 15)) * TT) * 7 + kx;
    } else {
        is_ld = (tid < 208);                     // 13 col-quads x 16 samps
        const int jc   = tid >> 4;               // 0..12 (col quad)
        const int samp = tid & 15;
        a_st = addr2B(samp, 52 + 4 * jc);        // 4-col group, aligned
        gb   = rin_g + (size_t)(4 * jc) * 16 + samp;  // col-major: col*16+samp
    }

    // ---- init ------------------------------------------------------------
    for (int i = tid; i < 2048; i += 448) {
        ((unsigned*)Ahi)[i] = 0u;
        ((unsigned*)Alo)[i] = 0u;
    }
    if (l == 6) {
        for (int i = tid; i < 2 * 16 * 52; i += 448) ((float*)h_sh)[i] = 0.0f;
        for (int i = tid; i < 7 * 52; i += 448) {
            const int o = i / 52, k = i - o * 52;
            w7[o][k] = (k < HH) ? fcw[o * HH + k] : 0.0f;
        }
        if (tid < 7) bsh[tid] = fcb[tid];
    }
    __syncthreads();

    if (l > 0) {                                 // wait for input block 0
        if (actor) {
            while (flag_ld(flag_in) < 1) __builtin_amdgcn_s_sleep(1);
        }
        WGBAR();
    }

    // prologue: stage x_0 -> A[0]; x_1 -> slot fB (consumed at t=0 C phase)
    float4 fA = {0, 0, 0, 0}, fB = {0, 0, 0, 0};
    if (is_ld) {
        if (l == 0) {
            short h_, l_;
            bf16split(gb[0], h_, l_);
            Ahi[0][a_st] = h_; Alo[0][a_st] = l_;
            fB.x = gb[7];
        } else {
            float4 x0, x1;
            x0.x = ring_ldf(gb);      x0.y = ring_ldf(gb + 16);
            x0.z = ring_ldf(gb + 32); x0.w = ring_ldf(gb + 48);
            x1.x = ring_ldf(gb + SLOT_STEP);      x1.y = ring_ldf(gb + SLOT_STEP + 16);
            x1.z = ring_ldf(gb + SLOT_STEP + 32); x1.w = ring_ldf(gb + SLOT_STEP + 48);
            short h0,l0_,h1,l1_,h2,l2_,h3,l3_;
            bf16split(x0.x,h0,l0_); bf16split(x0.y,h1,l1_);
            bf16split(x0.z,h2,l2_); bf16split(x0.w,h3,l3_);
            short4v vh = {h0,h1,h2,h3}, vl = {l0_,l1_,l2_,l3_};
            *(short4v*)&Ahi[0][a_st] = vh;
            *(short4v*)&Alo[0][a_st] = vl;
            fB = x1;
        }
    }
    __syncthreads();

    // ---- scan ------------------------------------------------------------
    for (int t = 0; t < TT; ++t) {
        const int p  = t & 1;
        const int tb = t & 7;

        // A: producer chores — per-wave drain (tb2), publish (tb3). The
        // end-of-step WGBAR between them orders all drains before the store.
        if (wr && tb == 2) VMDRAIN();
        if (wr && tb == 3 && (t >> 3) >= 1 && actor)
            flag_st(flag_out, t >> 3);

        // B1: consumer gate — the first load of block m+1 (x_{8m+8}) is
        // issued at this step's D phase (t+2 = 8m+8); require it published.
        if (l > 0 && tb == 6 && (t + 2) < TT) {
            if (actor) {
                const int want = ((t + 2) >> 3) + 1;
                while (flag_ld(flag_in) < want) __builtin_amdgcn_s_sleep(1);
            }
            WGBAR();
        }
        // B2: consumer signal — every loader wave register-consumed its
        // block-m loads at C of step 8m+6 (vmcnt-waited there) and the
        // step barrier ordered all waves past it; no drain needed.
        if (l > 0 && tb == 7 && actor)
            flag_st(cons_sig, (t >> 3) + 1);

        // D: issue load of x_{t+2} (2-step prefetch; lands in fA/fB at the
        // step tail, consumed next step — ~1 full step of latency hide)
        const bool ldnow = is_ld && (t + 2) < TT;
        float4 xnew = {0, 0, 0, 0};
        if (ldnow) {
            if (l == 0) {
                xnew.x = gb[(size_t)(t + 2) * 7];
            } else {
                const int offn = (((t + 2) >> 3) & (RW - 1)) * SLOT_BLK
                               + ((t + 2) & 7) * SLOT_STEP;
                xnew.x = ring_ldf(gb + offn);
                xnew.y = ring_ldf(gb + offn + 16);
                xnew.z = ring_ldf(gb + offn + 32);
                xnew.w = ring_ldf(gb + offn + 48);
            }
        }

        // E: A fragments (parity p), conflict-free b128 + MFMA + preT
        short8 AH[4], AL[4];
        #pragma unroll
        for (int ks = 0; ks < 4; ++ks) {
            if (ks < KSRT) {
                AH[ks] = *(const short8*)&Ahi[p][ks * 512 + lane * 8];
                AL[ks] = *(const short8*)&Alo[p][ks * 512 + lane * 8];
            }
        }

        f32x4 C0 = {biasv[0], biasv[0], biasv[0], biasv[0]};
        #pragma unroll
        for (int ks = 0; ks < 4; ++ks) {
            if (ks < KSRT) {
                C0 = __builtin_amdgcn_mfma_f32_16x16x32_bf16(AH[ks], BH[0][ks], C0, 0, 0, 0);
                C0 = __builtin_amdgcn_mfma_f32_16x16x32_bf16(AL[ks], BH[0][ks], C0, 0, 0, 0);
                C0 = __builtin_amdgcn_mfma_f32_16x16x32_bf16(AH[ks], BL[0][ks], C0, 0, 0, 0);
            }
        }
        #pragma unroll
        for (int r = 0; r < 4; ++r)
            preT[(tA * 16 + 4 * quad + r) * 20 + lrow] = C0[r];

        if (wave < 6) {
            f32x4 C1 = {biasv[1], biasv[1], biasv[1], biasv[1]};
            #pragma unroll
            for (int ks = 0; ks < 4; ++ks) {
                if (ks < KSRT) {
                    C1 = __builtin_amdgcn_mfma_f32_16x16x32_bf16(AH[ks], BH[1][ks], C1, 0, 0, 0);
                    C1 = __builtin_amdgcn_mfma_f32_16x16x32_bf16(AL[ks], BH[1][ks], C1, 0, 0, 0);
                    C1 = __builtin_amdgcn_mfma_f32_16x16x32_bf16(AH[ks], BL[1][ks], C1, 0, 0, 0);
                }
            }
            #pragma unroll
            for (int r = 0; r < 4; ++r)
                preT[(tB * 16 + 4 * quad + r) * 20 + lrow] = C1[r];
        }

        // F: fused FC (layer 6): consume h_{t-1} from h_sh[p]
        if (l == 6 && t > 0 && tid < 112) {
            const int s = tid / 7;
            const int o = tid - s * 7;
            const float* hr = h_sh[p][s];
            float acc = bsh[o];
            #pragma unroll
            for (int k = 0; k < 52; k += 4) {
                const f32x4 hv4 = *(const f32x4*)&hr[k];
                const f32x4 wv4 = *(const f32x4*)&w7[o][k];
                acc = fmaf(hv4.x, wv4.x, acc);
                acc = fmaf(hv4.y, wv4.y, acc);
                acc = fmaf(hv4.z, wv4.z, acc);
                acc = fmaf(hv4.w, wv4.w, acc);
            }
            outp[((size_t)(b0 + s) * TT + (t - 1)) * 7 + o] = acc;
        }

        // G: EW. Tile A runs on ALL lanes: pad lanes (j0=49..51) have zero
        // B rows + zero bias -> gates==0 -> hv==0 exactly, so the store is
        // one coalesced 256B wave store incl. pads.
        const int offc = ((t >> 3) & (RW - 1)) * SLOT_BLK + tb * SLOT_STEP;
        {
            const f32x4 gt = *(const f32x4*)&preT[(tA * 16 + lrow) * 20 + 4 * quad];
            const float i_ = sigmoidf_(gt.x);
            const float f_ = sigmoidf_(gt.y);
            const float g_ = tanhf_(gt.z);
            const float o_ = sigmoidf_(gt.w);
            cc0 = f_ * cc0 + i_ * g_;
            const float hv = o_ * tanhf_(cc0);
            short hh, hl;
            bf16split(hv, hh, hl);
            Ahi[p ^ 1][ah0] = hh;
            Alo[p ^ 1][ah0] = hl;
            if (wr) ring_st(rc0 + offc, hv);
            else    h_sh[p ^ 1][lrow][j0] = hv;
        }
        if (v1) {
            const f32x4 gt = *(const f32x4*)&preT[(tB * 16 + lrow) * 20 + 4 * quad];
            const float i_ = sigmoidf_(gt.x);
            const float f_ = sigmoidf_(gt.y);
            const float g_ = tanhf_(gt.z);
            const float o_ = sigmoidf_(gt.w);
            cc1 = f_ * cc1 + i_ * g_;
            const float hv = o_ * tanhf_(cc1);
            short hh, hl;
            bf16split(hv, hh, hl);
            Ahi[p ^ 1][ah1] = hh;
            Alo[p ^ 1][ah1] = hl;
            if (wr) ring_st(rc1 + offc, hv);
            else    h_sh[p ^ 1][lrow][j1] = hv;
        }

        // C: stage x_{t+1} from slot (t+1)&1; refill slot (t+2)&1 with xnew
        if (is_ld && (t + 1) < TT) {
            const float4 xv = p ? fA : fB;
            if (l == 0) {
                short h_, l_;
                bf16split(xv.x, h_, l_);
                Ahi[p ^ 1][a_st] = h_; Alo[p ^ 1][a_st] = l_;
            } else {
                short h0,l0_,h1,l1_,h2,l2_,h3,l3_;
                bf16split(xv.x,h0,l0_); bf16split(xv.y,h1,l1_);
                bf16split(xv.z,h2,l2_); bf16split(xv.w,h3,l3_);
                short4v vh = {h0,h1,h2,h3}, vl = {l0_,l1_,l2_,l3_};
                *(short4v*)&Ahi[p ^ 1][a_st] = vh;
                *(short4v*)&Alo[p ^ 1][a_st] = vl;
            }
        }
        if (ldnow) { if (p) fB = xnew; else fA = xnew; }

        // H: producer wrap gate — before entering block k=(t+1)>>3, slot
        // k%RW must be consumed (cons >= k-RW+1). Actor polls; the step-end
        // barrier holds everyone else; block-k stores come after it.
        if (wr && tb == 7 && (t + 1) < TT && ((t + 1) >> 3) >= RW && actor) {
            const int need = ((t + 1) >> 3) - RW + 1;
            while (flag_ld(cons_poll) < need) __builtin_amdgcn_s_sleep(1);
        }

        WGBAR();   // lgkm-only: A[p^1] + preT + h_sh reuse safe; vm stores
                   // stay in flight (drained only at the tb2 chore)
    }

    // fused FC epilogue: h_511 was written to h_sh[0] (t=511, p=1)
    if (l == 6 && tid < 112) {
        const int s = tid / 7;
        const int o = tid - s * 7;
        const float* hr = h_sh[0][s];
        float acc = bsh[o];
        #pragma unroll
        for (int k = 0; k < 52; k += 4) {
            const f32x4 hv4 = *(const f32x4*)&hr[k];
            const f32x4 wv4 = *(const f32x4*)&w7[o][k];
            acc = fmaf(hv4.x, wv4.x, acc);
            acc = fmaf(hv4.y, wv4.y, acc);
            acc = fmaf(hv4.z, wv4.z, acc);
            acc = fmaf(hv4.w, wv4.w, acc);
        }
        outp[((size_t)(b0 + s) * TT + 511) * 7 + o] = acc;
    }

    // epilogue: publish completion (covers blocks 56..63)
    if (wr) {
        VMDRAIN();
        __syncthreads();
        if (actor)
            flag_st(flag_out, 64);
    }
}

// ======================= fallback path (R4, per-layer) ======================

template<int DIN>
__global__ __launch_bounds__(448)
void lstm_fb(const float* xin, float* hout,
             const float* __restrict__ Wih, const float* __restrict__ Whh,
             const float* __restrict__ bihp, const float* __restrict__ bhhp)
{
    constexpr int XO = 52;
    constexpr int KTOT = XO + DIN;
    constexpr int KSTEPS = (KTOT + 31) / 32;
    __shared__ short Ahi[2][KSTEPS * 512];
    __shared__ short Alo[2][KSTEPS * 512];
    __shared__ float preT[13 * 64];

    const int tid = threadIdx.x, wave = tid >> 6, lane = tid & 63;
    const int quad = lane >> 4, lrow = lane & 15;
    const int b0 = blockIdx.x * 4;
    const int ntiles = (wave < 6) ? 2 : 1;
    const int tileA = (wave < 6) ? wave : 12;
    const int tileB = wave + 6;

    short8 BH[2][KSTEPS], BL[2][KSTEPS];
    float biasv[2];
    #pragma unroll
    for (int ti = 0; ti < 2; ++ti) {
        const int nt = ti ? tileB : tileA;
        const bool valid = (ti < ntiles);
        const int np = nt * 16 + lrow, j = np >> 2, g = np & 3;
        biasv[ti] = (valid && j < HH) ? (bihp[g*HH+j] + bhhp[g*HH+j]) : 0.0f;
        #pragma unroll
        for (int ks = 0; ks < KSTEPS; ++ks)
            #pragma unroll
            for (int jj = 0; jj < 8; ++jj) {
                const int k = ks * 32 + quad * 8 + jj;
                float wv = 0.0f;
                if (valid && j < HH) {
                    const int r = g * HH + j;
                    if (k < HH) wv = Whh[r * HH + k];
                    else if (k >= XO && k < KTOT) wv = Wih[r * DIN + (k - XO)];
                }
                short h_, l_; bf16split(wv, h_, l_);
                BH[ti][ks][jj] = h_; BL[ti][ks][jj] = l_;
            }
    }

    const int ec = lane & 15, ew_jj = ec >> 2, ew_m = ec & 3, ew_ti = lane >> 4;
    const bool is_ew = (lane < 32) && (ew_ti < ntiles);
    const int ew_nt = ew_ti ? tileB : tileA;
    const int ew_j = 4 * ew_nt + ew_jj;
    const bool ew_ok = is_ew && (ew_j < HH);
    const int pa0 = (ew_nt*16 + 4*ew_jj + 0)*4 + ew_m;
    const int pa1 = (ew_nt*16 + 4*ew_jj + 1)*4 + ew_m;
    const int pa2 = (ew_nt*16 + 4*ew_jj + 2)*4 + ew_m;
    const int pa3 = (ew_nt*16 + 4*ew_jj + 3)*4 + ew_m;
    const int ew_ah = addr2B(ew_m, ew_j);
    float cc = 0.0f;

    const int lx = tid;
    const bool is_loader = (lx < 4 * DIN);
    const int ld_m = is_loader ? (lx & 3) : 0, ld_k = is_loader ? (lx >> 2) : 0;
    const int xaddr = addr2B(ld_m, XO + ld_k);
    const size_t xbase = ((size_t)(b0 + ld_m) * TT) * DIN + ld_k;
    float* houtp = hout + ((size_t)(b0 + ew_m) * TT) * HH + (ew_ok ? ew_j : 0);

    for (int i = tid; i < KSTEPS * 512; i += 448) {
        ((unsigned*)Ahi)[i] = 0u; ((unsigned*)Alo)[i] = 0u;
    }
    __syncthreads();
    if (is_loader) {
        short h_, l_; bf16split(xin[xbase], h_, l_);
        Ahi[0][xaddr] = h_; Alo[0][xaddr] = l_;
    }
    __syncthreads();

    for (int t = 0; t < TT; ++t) {
        const int p = t & 1;
        float xnext = 0.0f;
        if (is_loader && (t + 1 < TT)) xnext = xin[xbase + (size_t)(t+1) * DIN];

        short8 AH[KSTEPS], AL[KSTEPS];
        #pragma unroll
        for (int ks = 0; ks < KSTEPS; ++ks) {
            AH[ks] = *(const short8*)&Ahi[p][ks * 512 + lane * 8];
            AL[ks] = *(const short8*)&Alo[p][ks * 512 + lane * 8];
        }
        #pragma unroll
        for (int ti = 0; ti < 2; ++ti) {
            f32x4 C = {biasv[ti], biasv[ti], biasv[ti], biasv[ti]};
            #pragma unroll
            for (int ks = 0; ks < KSTEPS; ++ks) {
                C = __builtin_amdgcn_mfma_f32_16x16x32_bf16(AH[ks], BH[ti][ks], C, 0, 0, 0);
                C = __builtin_amdgcn_mfma_f32_16x16x32_bf16(AL[ks], BH[ti][ks], C, 0, 0, 0);
                C = __builtin_amdgcn_mfma_f32_16x16x32_bf16(AH[ks], BL[ti][ks], C, 0, 0, 0);
            }
            if (ti < ntiles && lane < 16) {
                const int nt = ti ? tileB : tileA;
                *(f32x4*)&preT[(nt * 16 + lrow) * 4] = C;
            }
        }
        if (is_ew) {
            const float i_ = sigmoidf_(preT[pa0]);
            const float f_ = sigmoidf_(preT[pa1]);
            const float g_ = tanhf_(preT[pa2]);
            const float o_ = sigmoidf_(preT[pa3]);
            cc = f_ * cc + i_ * g_;
            const float hv = o_ * tanhf_(cc);
            if (ew_ok) {
                short hh, hl; bf16split(hv, hh, hl);
                Ahi[p ^ 1][ew_ah] = hh; Alo[p ^ 1][ew_ah] = hl;
                houtp[(size_t)t * HH] = hv;
            }
        }
        if (is_loader && (t + 1 < TT)) {
            short h_, l_; bf16split(xnext, h_, l_);
            Ahi[p ^ 1][xaddr] = h_; Alo[p ^ 1][xaddr] = l_;
        }
        __syncthreads();
    }
}

__global__ __launch_bounds__(256)
void fc_fb(const float* __restrict__ hbuf, const float* __restrict__ fcw,
           const float* __restrict__ fcb, float* __restrict__ outp)
{
    constexpr int HP = 52;
    __shared__ float w[7][HP];
    __shared__ float bsh[8];
    const int tid = threadIdx.x;
    for (int i = tid; i < 7 * HP; i += 256) {
        const int o = i / HP, k = i - o * HP;
        w[o][k] = (k < HH) ? fcw[o * HH + k] : 0.0f;
    }
    if (tid < 7) bsh[tid] = fcb[tid];
    __syncthreads();
    const size_t i = (size_t)blockIdx.x * 256 + tid;
    float acc[7];
    #pragma unroll
    for (int j = 0; j < 7; ++j) acc[j] = bsh[j];
    const float* hp = hbuf + i * HH;
    #pragma unroll
    for (int k = 0; k < HH; ++k) {
        const float hv = hp[k];
        #pragma unroll
        for (int j = 0; j < 7; ++j) acc[j] = fmaf(hv, w[j][k], acc[j]);
    }
    #pragma unroll
    for (int j = 0; j < 7; ++j) outp[i * 7 + j] = acc[j];
}

extern "C" void kernel_launch(void* const* d_in, const int* in_sizes, int n_in,
                              void* d_out, int out_size, void* d_ws, size_t ws_size,
                              hipStream_t stream)
{
    const float* x    = (const float*)d_in[0];
    const float* Wih0 = (const float*)d_in[1];
    const float* Wihr = (const float*)d_in[2];
    const float* Whh  = (const float*)d_in[3];
    const float* bih  = (const float*)d_in[4];
    const float* bhh  = (const float*)d_in[5];
    const float* fcw  = (const float*)d_in[6];
    const float* fcb  = (const float*)d_in[7];
    float* outp = (float*)d_out;

    if (ws_size >= WS_NEEDED) {
        float* ring  = (float*)d_ws;
        int*   flags = (int*)((char*)d_ws + RING_FLOATS * 4);
        zero_flags<<<(int)((FLAG_INTS + 255) / 256), 256, 0, stream>>>(
            flags, (int)FLAG_INTS);
        lstm_pipe<<<448, 448, 0, stream>>>(x, ring, flags, Wih0, Wihr,
                                           Whh, bih, bhh, fcw, fcb, outp);
    } else {
        float* hbuf = (float*)d_ws;   // [B,T,49]
        lstm_fb<7><<<BB / 4, 448, 0, stream>>>(x, hbuf, Wih0, Whh, bih, bhh);
        for (int l = 1; l < 7; ++l) {
            lstm_fb<49><<<BB / 4, 448, 0, stream>>>(
                hbuf, hbuf,
                Wihr + (size_t)(l - 1) * GG * HH,
                Whh  + (size_t)l * GG * HH,
                bih  + (size_t)l * GG,
                bhh  + (size_t)l * GG);
        }
        fc_fb<<<(BB * TT) / 256, 256, 0, stream>>>(hbuf, fcw, fcb, outp);
    }
}